// Round 7
// baseline (260.907 us; speedup 1.0000x reference)
//
#include <hip/hip_runtime.h>
#include <hip/hip_bf16.h>
#include <stdint.h>

// ---------------------------------------------------------------------------
// DMF: Monte-Carlo mutation fusion, bit-exact JAX threefry2x32 reproduction
// (jax_threefry_partitionable=True). History:
//   R1 naive: 634us. R2 mask-gated noise compaction: 286us.
//   R3 asm rotl + 4-way unroll + packed queue: 249.5us.
//   R4 dual-chain 128-item flush: 273.6us REGRESSION.
//   R5 branchless queue writes: 248.6us (neutral).
//   R6 lag-one pipelined flush: 250.3us (neutral). => flush ds_read latency
//      was never the stall. VALUBusy~101% is gfx94x-formula (4cyc/instr);
//      gfx950 SIMD-32 issues at 2cyc/instr => TRUE pipe util ~50%.
//      Static floor: 120 threefrys/lane forced by bit-exactness = 137us at
//      perfect issue, ~200us at m07's measured 66% issue efficiency.
// R7: ONE variable -- 8-way mask unroll. 8 independent threefry chains per
//     group = 584-instr branch-free ILP block; 12 groups + 4-tail instead of
//     25 groups (halves bookkeeping/branch boundaries). Lag-one machinery
//     dropped (neutral). Ring 1024: mid-group pending <= 63+512=575 < 1024,
//     no burst-drain needed.
// ---------------------------------------------------------------------------

#define NMUT 100
#define NB   1024
#define ND   512
#define NBD  (NB * ND)            // 2^19 per-mutation stride
#define NCOL 1024                 // output columns = 2*ND
// uniform(mb) < 0.2f  <=>  (mb>>9) < 1677722  <=>  mb < (1677722<<9)
#define MASK_THR 858993664u
#define QMASK 1023u               // 1024-deep ring
#define QDUMP 1024u               // dump region: slot 1024+lane (per-lane)

#ifdef __HIP_DEVICE_COMPILE__
template <int R>
__device__ __forceinline__ uint32_t rotl1(uint32_t x) {
  uint32_t d;
  asm("v_alignbit_b32 %0, %1, %1, %2" : "=v"(d) : "v"(x), "n"(32 - R));
  return d;
}
#define ROTL(x, r) rotl1<(r)>(x)
#else
#define ROTL(x, r) (((x) << (r)) | ((x) >> (32 - (r))))
#endif

__host__ __device__ __forceinline__ void tf2x32(uint32_t k0, uint32_t k1,
                                                uint32_t c0, uint32_t c1,
                                                uint32_t& o0, uint32_t& o1) {
  uint32_t ks2 = k0 ^ k1 ^ 0x1BD11BDAu;
  uint32_t x0 = c0 + k0;
  uint32_t x1 = c1 + k1;
#define TFR(r) { x0 += x1; x1 = ROTL(x1, r); x1 ^= x0; }
  TFR(13) TFR(15) TFR(26) TFR(6)
  x0 += k1;  x1 += ks2 + 1u;
  TFR(17) TFR(29) TFR(16) TFR(24)
  x0 += ks2; x1 += k0 + 2u;
  TFR(13) TFR(15) TFR(26) TFR(6)
  x0 += k0;  x1 += k1 + 3u;
  TFR(17) TFR(29) TFR(16) TFR(24)
  x0 += k1;  x1 += ks2 + 4u;
  TFR(13) TFR(15) TFR(26) TFR(6)
  x0 += ks2; x1 += k0 + 5u;
#undef TFR
  o0 = x0; o1 = x1;
}

__device__ __forceinline__ uint32_t rbits32(uint32_t k0, uint32_t k1, uint32_t idx) {
  uint32_t a, b;
  tf2x32(k0, k1, 0u, idx, a, b);
  return a ^ b;
}

__device__ __forceinline__ uint32_t mbcnt64(uint64_t m) {
  return __builtin_amdgcn_mbcnt_hi((uint32_t)(m >> 32),
         __builtin_amdgcn_mbcnt_lo((uint32_t)m, 0u));
}

// XLA ErfInv (f32), Giles polynomial. Far branch (w>=5, ~0.33%/lane) is
// wave-voted: skipped when no lane needs it (~80% of flush batches).
__device__ __forceinline__ float erfinv_wv(float x) {
  float w = -__logf(__builtin_fmaf(-x, x, 1.0f));
  float wa = w - 2.5f;
  float p = 2.81022636e-08f;
  p = __builtin_fmaf(p, wa, 3.43273939e-07f);
  p = __builtin_fmaf(p, wa, -3.5233877e-06f);
  p = __builtin_fmaf(p, wa, -4.39150654e-06f);
  p = __builtin_fmaf(p, wa, 0.00021858087f);
  p = __builtin_fmaf(p, wa, -0.00125372503f);
  p = __builtin_fmaf(p, wa, -0.00417768164f);
  p = __builtin_fmaf(p, wa, 0.246640727f);
  p = __builtin_fmaf(p, wa, 1.50140941f);
  if (__ballot(w >= 5.0f)) {
    float wb = __builtin_amdgcn_sqrtf(w) - 3.0f;
    float p2 = -0.000200214257f;
    p2 = __builtin_fmaf(p2, wb, 0.000100950558f);
    p2 = __builtin_fmaf(p2, wb, 0.00134934322f);
    p2 = __builtin_fmaf(p2, wb, -0.00367342844f);
    p2 = __builtin_fmaf(p2, wb, 0.00573950773f);
    p2 = __builtin_fmaf(p2, wb, -0.0076224613f);
    p2 = __builtin_fmaf(p2, wb, 0.00943887047f);
    p2 = __builtin_fmaf(p2, wb, 1.00167406f);
    p2 = __builtin_fmaf(p2, wb, 2.83297682f);
    p = (w < 5.0f) ? p : p2;
  }
  return p * x;
}

// ---- Kernel A: per-row std, ddof=1. blocks 0..1023 spatial, 1024..2047 spectral.
__global__ __launch_bounds__(256) void dmf_std(const float* __restrict__ spatial,
                                               const float* __restrict__ spectral,
                                               float* __restrict__ stds) {
  __shared__ float part[4];
  uint32_t tid = threadIdx.x, w = tid >> 6, lane = tid & 63u;
  uint32_t r = blockIdx.x;
  const float* feat = (r >= NB) ? spectral : spatial;
  uint32_t row = r & (NB - 1);
  float v0 = feat[row * ND + tid];
  float v1 = feat[row * ND + tid + 256];
  float s = v0 + v1;
  for (int d = 1; d < 64; d <<= 1) s += __shfl_xor(s, d, 64);
  if (lane == 0) part[w] = s;
  __syncthreads();
  float mean = (part[0] + part[1] + part[2] + part[3]) * (1.0f / ND);
  float d0 = v0 - mean, d1 = v1 - mean;
  float s2 = __builtin_fmaf(d0, d0, d1 * d1);
  for (int d = 1; d < 64; d <<= 1) s2 += __shfl_xor(s2, d, 64);
  __syncthreads();                    // protect part[] reuse
  if (lane == 0) part[w] = s2;
  __syncthreads();
  if (tid == 0)
    stds[r] = __builtin_sqrtf((part[0] + part[1] + part[2] + part[3]) * (1.0f / (ND - 1)));
}

// ---- Kernel B: one thread per output element; wave-local noise work queue.
__global__ __launch_bounds__(256) void dmf_main(
    const float* __restrict__ spatial, const float* __restrict__ spectral,
    const float* __restrict__ stds, float* __restrict__ colsum,
    float* __restrict__ outP,
    uint32_t km1a, uint32_t km1b, uint32_t kn1a, uint32_t kn1b,
    uint32_t km2a, uint32_t km2b, uint32_t kn2a, uint32_t kn2b) {
  __shared__ uint32_t q[4][1088];  // [0..1023] ring; [1024..1087] per-lane dump
  __shared__ float accd[4][64];    // per-wave: sum delta
  __shared__ float accd2[4][64];   // per-wave: sum delta^2

  const uint32_t tid  = threadIdx.x;
  const uint32_t w    = tid >> 6;
  const uint32_t lane = tid & 63u;
  const uint32_t g    = blockIdx.x * 256u + tid;
  // Wave-uniform geometry: waves are 64-aligned in g, never cross b or the
  // spatial/spectral boundary (both multiples of 64).
  const uint32_t g0   = g & ~63u;
  const uint32_t b    = g0 >> 10;
  const uint32_t j0   = g0 & (NCOL - 1);
  const uint32_t t    = j0 >> 9;
  const uint32_t d0   = j0 & (ND - 1);
  const uint32_t off0 = b * ND + d0;

  uint32_t* __restrict__ wq  = q[w];
  float*    __restrict__ pa  = accd[w];
  float*    __restrict__ pa2 = accd2[w];

  pa[lane]  = 0.0f;
  pa2[lane] = 0.0f;

  const uint32_t mk0 = t ? km2a : km1a, mk1 = t ? km2b : km1b;
  const uint32_t nk0 = t ? kn2a : kn1a, nk1 = t ? kn2b : kn1b;
  const float sstd = 1.41421356237309505f * stds[t * NB + b];  // sqrt(2)*std
  const uint32_t dumpslot = QDUMP + lane;    // per-lane dump slot

  auto flush_item = [&](uint32_t pk) {       // pk = (m<<19)|ownerLane
    uint32_t LL = pk & 63u;
    uint32_t nidx = off0 + pk;               // == m*2^19 + off0 + LL (no carry)
    uint32_t nb = rbits32(nk0, nk1, nidx);
    float nf = __uint_as_float(0x3F800000u | (nb >> 9)) - 1.0f;  // [0,1)
    // uniform(lo=-0.99999994, hi=1): (hi-lo) == 2.0f exactly; nf>=0 => >= lo
    float un = __builtin_fmaf(nf, 2.0f, -0.99999994f);
    float nrm = erfinv_wv(un) * sstd;
    atomicAdd(&pa[LL], nrm);
    atomicAdd(&pa2[LL], nrm * nrm);
  };

  uint32_t qcount = 0, qdone = 0;
  uint32_t idx = off0 + lane;

  // 12 groups of 8 draws: 8 independent threefry chains, one straightline
  // branch-free ILP block per group; then a 4-draw tail (NMUT=100=8*12+4).
#pragma unroll 1
  for (uint32_t m = 0; m < 96u; m += 8) {
    uint32_t mbv[8];
#pragma unroll
    for (uint32_t k = 0; k < 8; ++k) mbv[k] = rbits32(mk0, mk1, idx + k * NBD);
    idx += 8u * NBD;
#pragma unroll
    for (uint32_t k = 0; k < 8; ++k) {
      uint64_t B = __ballot(mbv[k] < MASK_THR);
      uint32_t slot = (mbv[k] < MASK_THR) ? ((qcount + mbcnt64(B)) & QMASK)
                                          : dumpslot;
      wq[slot] = ((m + k) << 19) | lane;
      qcount += (uint32_t)__popcll(B);
    }
    // Mid-group pending <= 63 + 512 = 575 < 1024: ring never overwrites.
    while (qcount - qdone >= 64u) {
      flush_item(wq[(qdone + lane) & QMASK]);
      qdone += 64u;
    }
  }
  {  // tail group: draws m = 96..99
    uint32_t mbv[4];
#pragma unroll
    for (uint32_t k = 0; k < 4; ++k) mbv[k] = rbits32(mk0, mk1, idx + k * NBD);
#pragma unroll
    for (uint32_t k = 0; k < 4; ++k) {
      uint64_t B = __ballot(mbv[k] < MASK_THR);
      uint32_t slot = (mbv[k] < MASK_THR) ? ((qcount + mbcnt64(B)) & QMASK)
                                          : dumpslot;
      wq[slot] = ((96u + k) << 19) | lane;
      qcount += (uint32_t)__popcll(B);
    }
    while (qcount - qdone >= 64u) {
      flush_item(wq[(qdone + lane) & QMASK]);
      qdone += 64u;
    }
  }
  uint32_t rem = qcount - qdone;   // <= 63
  if (lane < rem) flush_item(wq[(qdone + lane) & QMASK]);

  // DS ops from this wave complete in issue order: accumulators are final.
  float sd  = pa[lane];
  float sd2 = pa2[lane];

  const float* feat = t ? spectral : spatial;
  float x = feat[off0 + lane];
  float mean = sd * (1.0f / NMUT);
  float var = __builtin_fmaf(-mean, mean, sd2 * (1.0f / NMUT)) + 1e-6f;
  float iv = 1.0f / var;
  float S = __builtin_fmaf((float)NMUT, x, sd);     // sum_m c_m
  outP[g] = iv * S;
  atomicAdd(&colsum[j0 + lane], iv);
}

// ---- Kernel C: normalize by column sum of invvar.
__global__ __launch_bounds__(256) void dmf_norm(float* __restrict__ out,
                                                const float* __restrict__ colsum) {
  uint32_t g = blockIdx.x * 256u + threadIdx.x;
  out[g] = out[g] / colsum[g & (NCOL - 1)];
}

extern "C" void kernel_launch(void* const* d_in, const int* in_sizes, int n_in,
                              void* d_out, int out_size, void* d_ws, size_t ws_size,
                              hipStream_t stream) {
  const float* spatial  = (const float*)d_in[0];
  const float* spectral = (const float*)d_in[1];
  float* out = (float*)d_out;
  float* ws = (float*)d_ws;
  float* colsum = ws;            // [1024]
  float* stds   = ws + 1024;     // [2048]

  // Derive the 4 split keys of jax.random.key(42) on the host (pure u32 math;
  // partitionable split is fold-like: key_i = threefry2x32(key, (0, i))).
  uint32_t keys[4][2];
  for (uint32_t i = 0; i < 4; ++i)
    tf2x32(0u, 42u, 0u, i, keys[i][0], keys[i][1]);

  hipMemsetAsync(colsum, 0, NCOL * sizeof(float), stream);
  dmf_std<<<2 * NB, 256, 0, stream>>>(spatial, spectral, stds);
  dmf_main<<<(NB * NCOL) / 256, 256, 0, stream>>>(
      spatial, spectral, stds, colsum, out,
      keys[0][0], keys[0][1], keys[1][0], keys[1][1],
      keys[2][0], keys[2][1], keys[3][0], keys[3][1]);
  dmf_norm<<<(NB * NCOL) / 256, 256, 0, stream>>>(out, colsum);
}

// Round 8
// 248.424 us; speedup vs baseline: 1.0502x; 1.0502x over previous
//
#include <hip/hip_runtime.h>
#include <hip/hip_bf16.h>
#include <stdint.h>

// ---------------------------------------------------------------------------
// DMF: Monte-Carlo mutation fusion, bit-exact JAX threefry2x32 reproduction
// (jax_threefry_partitionable=True). History:
//   R1 naive: 634us. R2 mask-gated noise compaction: 286us.
//   R3 asm rotl + 4-way unroll + packed queue: 249.5us.
//   R4 dual-chain 128-item flush: 273.6us REGRESSION.
//   R5 branchless queue writes: 248.6us BEST.
//   R6 lag-one pipelined flush: 250.3us (neutral -> DS latency not the stall).
//   R7 8-way unroll: 260.9us REGRESSION (wider block hurts scheduling).
// R8: revert to R5 verbatim -- the measured local optimum. Roofline argument:
//   irreducible 120 threefrys/lane (bit-exactness) = ~10.3k wave-instrs;
//   at m07's measured 66% sustained VALU issue -> ~208us floor for dmf_main;
//   measured ~240us (1.15x), residual = DS/SALU/branch issue slots that four
//   structural experiments failed to compress. VALUBusy ~101%, MfmaUtil 0,
//   HBM 0.5%: pure VALU-issue-bound. This is the roofline.
// ---------------------------------------------------------------------------

#define NMUT 100
#define NB   1024
#define ND   512
#define NBD  (NB * ND)            // 2^19 per-mutation stride
#define NCOL 1024                 // output columns = 2*ND
// uniform(mb) < 0.2f  <=>  (mb>>9) < 1677722  <=>  mb < (1677722<<9)
#define MASK_THR 858993664u
#define QDUMP 512u                // dump slot for masked-out queue writes

#ifdef __HIP_DEVICE_COMPILE__
template <int R>
__device__ __forceinline__ uint32_t rotl1(uint32_t x) {
  uint32_t d;
  // rotl(x,R) == ((x:x) >> (32-R)) -- one VOP3, shift is an inline constant.
  asm("v_alignbit_b32 %0, %1, %1, %2" : "=v"(d) : "v"(x), "n"(32 - R));
  return d;
}
#define ROTL(x, r) rotl1<(r)>(x)
#else
#define ROTL(x, r) (((x) << (r)) | ((x) >> (32 - (r))))
#endif

__host__ __device__ __forceinline__ void tf2x32(uint32_t k0, uint32_t k1,
                                                uint32_t c0, uint32_t c1,
                                                uint32_t& o0, uint32_t& o1) {
  uint32_t ks2 = k0 ^ k1 ^ 0x1BD11BDAu;
  uint32_t x0 = c0 + k0;
  uint32_t x1 = c1 + k1;
#define TFR(r) { x0 += x1; x1 = ROTL(x1, r); x1 ^= x0; }
  TFR(13) TFR(15) TFR(26) TFR(6)
  x0 += k1;  x1 += ks2 + 1u;
  TFR(17) TFR(29) TFR(16) TFR(24)
  x0 += ks2; x1 += k0 + 2u;
  TFR(13) TFR(15) TFR(26) TFR(6)
  x0 += k0;  x1 += k1 + 3u;
  TFR(17) TFR(29) TFR(16) TFR(24)
  x0 += k1;  x1 += ks2 + 4u;
  TFR(13) TFR(15) TFR(26) TFR(6)
  x0 += ks2; x1 += k0 + 5u;
#undef TFR
  o0 = x0; o1 = x1;
}

__device__ __forceinline__ uint32_t rbits32(uint32_t k0, uint32_t k1, uint32_t idx) {
  uint32_t a, b;
  tf2x32(k0, k1, 0u, idx, a, b);
  return a ^ b;
}

__device__ __forceinline__ uint32_t mbcnt64(uint64_t m) {
  return __builtin_amdgcn_mbcnt_hi((uint32_t)(m >> 32),
         __builtin_amdgcn_mbcnt_lo((uint32_t)m, 0u));
}

// XLA ErfInv (f32), Giles polynomial. Far branch (w>=5, ~0.33%/lane) is
// wave-voted: skipped when no lane needs it (~80% of flush batches).
__device__ __forceinline__ float erfinv_wv(float x) {
  float w = -__logf(__builtin_fmaf(-x, x, 1.0f));
  float wa = w - 2.5f;
  float p = 2.81022636e-08f;
  p = __builtin_fmaf(p, wa, 3.43273939e-07f);
  p = __builtin_fmaf(p, wa, -3.5233877e-06f);
  p = __builtin_fmaf(p, wa, -4.39150654e-06f);
  p = __builtin_fmaf(p, wa, 0.00021858087f);
  p = __builtin_fmaf(p, wa, -0.00125372503f);
  p = __builtin_fmaf(p, wa, -0.00417768164f);
  p = __builtin_fmaf(p, wa, 0.246640727f);
  p = __builtin_fmaf(p, wa, 1.50140941f);
  if (__ballot(w >= 5.0f)) {
    float wb = __builtin_amdgcn_sqrtf(w) - 3.0f;
    float p2 = -0.000200214257f;
    p2 = __builtin_fmaf(p2, wb, 0.000100950558f);
    p2 = __builtin_fmaf(p2, wb, 0.00134934322f);
    p2 = __builtin_fmaf(p2, wb, -0.00367342844f);
    p2 = __builtin_fmaf(p2, wb, 0.00573950773f);
    p2 = __builtin_fmaf(p2, wb, -0.0076224613f);
    p2 = __builtin_fmaf(p2, wb, 0.00943887047f);
    p2 = __builtin_fmaf(p2, wb, 1.00167406f);
    p2 = __builtin_fmaf(p2, wb, 2.83297682f);
    p = (w < 5.0f) ? p : p2;
  }
  return p * x;
}

// ---- Kernel A: per-row std, ddof=1. blocks 0..1023 spatial, 1024..2047 spectral.
__global__ __launch_bounds__(256) void dmf_std(const float* __restrict__ spatial,
                                               const float* __restrict__ spectral,
                                               float* __restrict__ stds) {
  __shared__ float part[4];
  uint32_t tid = threadIdx.x, w = tid >> 6, lane = tid & 63u;
  uint32_t r = blockIdx.x;
  const float* feat = (r >= NB) ? spectral : spatial;
  uint32_t row = r & (NB - 1);
  float v0 = feat[row * ND + tid];
  float v1 = feat[row * ND + tid + 256];
  float s = v0 + v1;
  for (int d = 1; d < 64; d <<= 1) s += __shfl_xor(s, d, 64);
  if (lane == 0) part[w] = s;
  __syncthreads();
  float mean = (part[0] + part[1] + part[2] + part[3]) * (1.0f / ND);
  float d0 = v0 - mean, d1 = v1 - mean;
  float s2 = __builtin_fmaf(d0, d0, d1 * d1);
  for (int d = 1; d < 64; d <<= 1) s2 += __shfl_xor(s2, d, 64);
  __syncthreads();                    // protect part[] reuse
  if (lane == 0) part[w] = s2;
  __syncthreads();
  if (tid == 0)
    stds[r] = __builtin_sqrtf((part[0] + part[1] + part[2] + part[3]) * (1.0f / (ND - 1)));
}

// ---- Kernel B: one thread per output element; wave-local noise work queue.
__global__ __launch_bounds__(256) void dmf_main(
    const float* __restrict__ spatial, const float* __restrict__ spectral,
    const float* __restrict__ stds, float* __restrict__ colsum,
    float* __restrict__ outP,
    uint32_t km1a, uint32_t km1b, uint32_t kn1a, uint32_t kn1b,
    uint32_t km2a, uint32_t km2b, uint32_t kn2a, uint32_t kn2b) {
  __shared__ uint32_t q[4][516];   // per-wave queue; slot 512 = dump (never read)
  __shared__ float accd[4][64];    // per-wave: sum delta   (2-way banks, free)
  __shared__ float accd2[4][64];   // per-wave: sum delta^2

  const uint32_t tid  = threadIdx.x;
  const uint32_t w    = tid >> 6;
  const uint32_t lane = tid & 63u;
  const uint32_t g    = blockIdx.x * 256u + tid;
  // Wave-uniform geometry: waves are 64-aligned in g, never cross b or the
  // spatial/spectral boundary (both multiples of 64).
  const uint32_t g0   = g & ~63u;
  const uint32_t b    = g0 >> 10;
  const uint32_t j0   = g0 & (NCOL - 1);
  const uint32_t t    = j0 >> 9;
  const uint32_t d0   = j0 & (ND - 1);
  const uint32_t off0 = b * ND + d0;

  uint32_t* __restrict__ wq  = q[w];
  float*    __restrict__ pa  = accd[w];
  float*    __restrict__ pa2 = accd2[w];

  pa[lane]  = 0.0f;
  pa2[lane] = 0.0f;

  const uint32_t mk0 = t ? km2a : km1a, mk1 = t ? km2b : km1b;
  const uint32_t nk0 = t ? kn2a : kn1a, nk1 = t ? kn2b : kn1b;
  const float sstd = 1.41421356237309505f * stds[t * NB + b];  // sqrt(2)*std

  auto flush_item = [&](uint32_t pk) {       // pk = (m<<19)|ownerLane
    uint32_t LL = pk & 63u;
    uint32_t nidx = off0 + pk;               // == m*2^19 + off0 + LL (no carry)
    uint32_t nb = rbits32(nk0, nk1, nidx);
    float nf = __uint_as_float(0x3F800000u | (nb >> 9)) - 1.0f;  // [0,1)
    // uniform(lo=-0.99999994, hi=1): (hi-lo) == 2.0f exactly; nf>=0 => >= lo
    float un = __builtin_fmaf(nf, 2.0f, -0.99999994f);
    float nrm = erfinv_wv(un) * sstd;
    atomicAdd(&pa[LL], nrm);
    atomicAdd(&pa2[LL], nrm * nrm);
  };

  uint32_t qcount = 0, qdone = 0;
  uint32_t idx = off0 + lane;
#pragma unroll 1
  for (uint32_t m = 0; m < NMUT; m += 4) {
    // four independent mask threefry chains for ILP
    uint32_t mb0 = rbits32(mk0, mk1, idx);
    uint32_t mb1 = rbits32(mk0, mk1, idx + NBD);
    uint32_t mb2 = rbits32(mk0, mk1, idx + 2u * NBD);
    uint32_t mb3 = rbits32(mk0, mk1, idx + 3u * NBD);
    idx += 4u * NBD;
    uint64_t B0 = __ballot(mb0 < MASK_THR);
    uint64_t B1 = __ballot(mb1 < MASK_THR);
    uint64_t B2 = __ballot(mb2 < MASK_THR);
    uint64_t B3 = __ballot(mb3 < MASK_THR);
    // Branchless compaction: every lane stores; non-survivors go to the dump
    // slot (same-address LDS stores broadcast-coalesce, never read back).
    uint32_t base = qcount;
    uint32_t s0 = (mb0 < MASK_THR) ? ((base + mbcnt64(B0)) & 511u) : QDUMP;
    base += (uint32_t)__popcll(B0);
    uint32_t s1 = (mb1 < MASK_THR) ? ((base + mbcnt64(B1)) & 511u) : QDUMP;
    base += (uint32_t)__popcll(B1);
    uint32_t s2 = (mb2 < MASK_THR) ? ((base + mbcnt64(B2)) & 511u) : QDUMP;
    base += (uint32_t)__popcll(B2);
    uint32_t s3 = (mb3 < MASK_THR) ? ((base + mbcnt64(B3)) & 511u) : QDUMP;
    qcount = base + (uint32_t)__popcll(B3);
    wq[s0] = (m << 19) | lane;
    wq[s1] = ((m + 1u) << 19) | lane;
    wq[s2] = ((m + 2u) << 19) | lane;
    wq[s3] = ((m + 3u) << 19) | lane;
    // pending entering group <=63, +<=256 => <=319 < 512: no overwrite.
    while (qcount - qdone >= 64u) {
      flush_item(wq[(qdone + lane) & 511u]);
      qdone += 64u;
    }
  }
  uint32_t rem = qcount - qdone;   // <= 63
  if (lane < rem) flush_item(wq[(qdone + lane) & 511u]);

  // DS ops from this wave complete in issue order: accumulators are final.
  float sd  = pa[lane];
  float sd2 = pa2[lane];

  const float* feat = t ? spectral : spatial;
  float x = feat[off0 + lane];
  float mean = sd * (1.0f / NMUT);
  float var = __builtin_fmaf(-mean, mean, sd2 * (1.0f / NMUT)) + 1e-6f;
  float iv = 1.0f / var;
  float S = __builtin_fmaf((float)NMUT, x, sd);     // sum_m c_m
  outP[g] = iv * S;
  atomicAdd(&colsum[j0 + lane], iv);
}

// ---- Kernel C: normalize by column sum of invvar.
__global__ __launch_bounds__(256) void dmf_norm(float* __restrict__ out,
                                                const float* __restrict__ colsum) {
  uint32_t g = blockIdx.x * 256u + threadIdx.x;
  out[g] = out[g] / colsum[g & (NCOL - 1)];
}

extern "C" void kernel_launch(void* const* d_in, const int* in_sizes, int n_in,
                              void* d_out, int out_size, void* d_ws, size_t ws_size,
                              hipStream_t stream) {
  const float* spatial  = (const float*)d_in[0];
  const float* spectral = (const float*)d_in[1];
  float* out = (float*)d_out;
  float* ws = (float*)d_ws;
  float* colsum = ws;            // [1024]
  float* stds   = ws + 1024;     // [2048]

  // Derive the 4 split keys of jax.random.key(42) on the host (pure u32 math;
  // partitionable split is fold-like: key_i = threefry2x32(key, (0, i))).
  uint32_t keys[4][2];
  for (uint32_t i = 0; i < 4; ++i)
    tf2x32(0u, 42u, 0u, i, keys[i][0], keys[i][1]);

  hipMemsetAsync(colsum, 0, NCOL * sizeof(float), stream);
  dmf_std<<<2 * NB, 256, 0, stream>>>(spatial, spectral, stds);
  dmf_main<<<(NB * NCOL) / 256, 256, 0, stream>>>(
      spatial, spectral, stds, colsum, out,
      keys[0][0], keys[0][1], keys[1][0], keys[1][1],
      keys[2][0], keys[2][1], keys[3][0], keys[3][1]);
  dmf_norm<<<(NB * NCOL) / 256, 256, 0, stream>>>(out, colsum);
}